// Round 19
// baseline (79.387 us; speedup 1.0000x reference)
//
#include <hip/hip_runtime.h>

#define N_ELEM 95
#define MAX_NODES 100096           // LDS z byte-table capacity
#define ZW_WORDS (MAX_NODES / 4)   // 25024 u32 words = 100096 B
#define RS2 20480                  // nodes per range (80 KB f32 acc in accum)
#define MAX_R2 5
#define EBLK 256                   // edge kernel blocks (1/CU, 100KB LDS)
#define CAP 4096                   // seg capacity per (block,range)

typedef float f32x4 __attribute__((ext_vector_type(4)));
typedef int   i32x4 __attribute__((ext_vector_type(4)));
typedef unsigned int u32;
typedef u32 u32x4 __attribute__((ext_vector_type(4)));
typedef unsigned long long u64;
typedef unsigned short u16;

__device__ __forceinline__ u32 bf16_rtn(float f) {           // f32 -> bf16 bits
    u32 u = __float_as_uint(f);
    return (u + 0x7FFFu + ((u >> 16) & 1u)) >> 16;
}

// build packed z byte-table in LDS directly from global z
__device__ __forceinline__ void build_ztab(
    u32* s_zw, const int* __restrict__ z, int n_words, int n_nodes, int tid, int nthr)
{
    for (int w = tid; w < n_words; w += nthr) {
        const int i = w << 2;
        u32 v;
        if (i + 4 <= n_nodes) {
            const i32x4 zz = ((const i32x4*)z)[w];
            v = ((u32)zz.x & 0xffu) | (((u32)zz.y & 0xffu) << 8)
              | (((u32)zz.z & 0xffu) << 16) | (((u32)zz.w & 0xffu) << 24);
        } else {
            v = 0u;
            for (int k = 0; k < 4 && i + k < n_nodes; ++k)
                v |= ((u32)z[i + k] & 0xffu) << (8 * k);
        }
        s_zw[w] = v;
    }
}

// ---------- A: compute values, emit surviving edges to per-range streams ----
// Full z byte-table in LDS (1 block/CU); 4 edges/thread-iter (finer quantum
// to cut the last-iteration quantization waste); rolling 2-stage pipeline.
__global__ __launch_bounds__(1024) void k_edge_split(
    const int*   __restrict__ z,
    const float* __restrict__ dist,
    const int*   __restrict__ sender,
    const int*   __restrict__ recv,
    const float* __restrict__ a_factor_p,
    const float* __restrict__ z_power_p,
    const float* __restrict__ coefs,
    const float* __restrict__ exps,
    const float* __restrict__ cradii,
    u32*         __restrict__ seg,      // [EBLK][Rr][CAP]
    u32*         __restrict__ counts,   // [EBLK][Rr]
    float*       __restrict__ out,      // pre-zeroed; receives overflow atomics
    int n_edges, int n_words, int n_nodes, int W, int Rr)
{
    __shared__ u32    s_zw[ZW_WORDS];
    __shared__ float2 s_tab[N_ELEM];    // {Z^Z_power, covalent_radius}
    __shared__ float  s_coef[4], s_exp[4], s_inv;
    __shared__ int    s_alleq;
    __shared__ u32    lcur[MAX_R2];         // block cursors per range
    __shared__ u32    s_base[16][MAX_R2];   // per-wave reserved bases

    const int tid  = threadIdx.x;
    const int lane = tid & 63;
    const int wid  = tid >> 6;

    build_ztab(s_zw, z, n_words, n_nodes, tid, 1024);
    if (tid < N_ELEM) {
        float zp = z_power_p[0];
        s_tab[tid] = make_float2(__powf((float)tid, zp), cradii[tid]);
    }
    if (tid < 4) { s_coef[tid] = coefs[tid]; s_exp[tid] = exps[tid]; }
    if (tid < MAX_R2) lcur[tid] = 0u;
    if (tid == 0) {
        s_inv = 1.0f / (a_factor_p[0] * 0.529f);
        s_alleq = (exps[0] == exps[1] && exps[1] == exps[2] && exps[2] == exps[3]);
    }
    __syncthreads();

    const unsigned char* s_zb = (const unsigned char*)s_zw;
    const float inv_pref = s_inv;
    const float c0 = s_coef[0], c1 = s_coef[1], c2 = s_coef[2], c3 = s_coef[3];
    const float e0 = s_exp[0],  e1 = s_exp[1],  e2 = s_exp[2],  e3 = s_exp[3];
    const float csum  = c0 + c1 + c2 + c3;
    const bool  alleq = (s_alleq != 0);

    const int n_grp = n_edges >> 2;     // groups of 4 edges
    const int b     = blockIdx.x;
    const int g0    = b * W;
    const int g1    = min(n_grp, g0 + W);

    if (g0 < g1) {
        const int n_iter = (g1 - g0 + 1023) >> 10;

        // stage 0: load iteration 0 (addresses clamped -> unconditional)
        int  gg  = g0 + tid;
        bool act = (gg < g1);
        int  g   = act ? gg : (g1 - 1);
        f32x4 dA = ((const f32x4*)dist)[g];
        i32x4 sA = ((const i32x4*)sender)[g];
        i32x4 rA = ((const i32x4*)recv)[g];

        for (int it = 0; it < n_iter; ++it) {
            // prefetch next iteration's 3 vector loads
            const int  gg2  = gg + 1024;
            const bool act2 = (gg2 < g1);
            const int  g2   = act2 ? gg2 : (g1 - 1);
            const f32x4 dA2 = ((const f32x4*)dist)[g2];
            const i32x4 sA2 = ((const i32x4*)sender)[g2];
            const i32x4 rA2 = ((const i32x4*)recv)[g2];

            float dd[4] = {dA.x, dA.y, dA.z, dA.w};
            int   ss[4] = {sA.x, sA.y, sA.z, sA.w};
            int   rr[4] = {rA.x, rA.y, rA.z, rA.w};

            int zu[4], zv[4];
            #pragma unroll
            for (int k = 0; k < 4; ++k) zu[k] = s_zb[ss[k]];
            #pragma unroll
            for (int k = 0; k < 4; ++k) zv[k] = s_zb[rr[k]];

            bool  em[4];
            float val[4];
            u32   entry[4], rgk[4];
            u64   cnt_pk = 0ull;

            #pragma unroll
            for (int k = 0; k < 4; ++k) {
                const float d = dd[k];
                const float2 tu = s_tab[zu[k]];
                const float2 tv = s_tab[zv[k]];
                const float powsum = tu.x + tv.x;
                const float rmax   = tu.y + tv.y;
                em[k] = act && (d < rmax);
                float o = 0.0f;
                if (em[k]) {
                    const float t   = __fdividef(d, rmax);
                    const float roa = d * powsum * inv_pref;
                    const float E0  = __expf(-e0 * roa);
                    float phi;
                    if (alleq) {
                        phi = csum * E0;           // 1 expf (uniform fast path)
                    } else {
                        phi = c0 * E0
                            + c1 * __expf(-e1 * roa)
                            + c2 * __expf(-e2 * roa)
                            + c3 * __expf(-e3 * roa);
                    }
                    const float v   = 7.1998f * (float)(zu[k] * zv[k]) * phi
                                    * __fdividef(1.0f, d);
                    const float t2  = t * t;
                    const float t6  = t2 * t2 * t2;
                    // p=6: 1 - 28 t^6 + 48 t^7 - 21 t^8
                    o = v * (1.0f - t6 * (28.0f - 48.0f * t + 21.0f * t2));
                }
                val[k] = o;
                const u32 rv  = (u32)rr[k];
                const u32 rg  = rv / (u32)RS2;
                rgk[k] = rg;
                entry[k] = ((rv - rg * (u32)RS2) << 16) | bf16_rtn(o);
                if (em[k]) cnt_pk += 1ull << (12 * rg);
            }

            // wave-wide inclusive scan of packed per-range counts (12-bit)
            u64 v = cnt_pk;
            #pragma unroll
            for (int d = 1; d < 64; d <<= 1) {
                u64 t = __shfl_up(v, (unsigned)d, 64);
                if (lane >= d) v += t;
            }
            const u64 excl = v - cnt_pk;

            // lane 63 holds wave totals: reserve block-level bases per range
            if (lane == 63) {
                for (int r = 0; r < Rr; ++r) {
                    const u32 tot = (u32)(v >> (12 * r)) & 0xFFFu;
                    s_base[wid][r] = tot ? atomicAdd(&lcur[r], tot) : lcur[r];
                }
            }

            // emit
            u64 run_pk = 0ull;
            #pragma unroll
            for (int k = 0; k < 4; ++k) {
                if (em[k]) {
                    const u32 rg  = rgk[k];
                    const u32 off = ((u32)(excl >> (12 * rg)) & 0xFFFu)
                                  + ((u32)(run_pk >> (12 * rg)) & 0xFFFu);
                    run_pk += 1ull << (12 * rg);
                    const u32 pos = s_base[wid][rg] + off;
                    if (pos < (u32)CAP)
                        seg[((size_t)b * Rr + rg) * CAP + pos] = entry[k];
                    else
                        unsafeAtomicAdd(&out[rr[k]], val[k]);
                }
            }

            // rotate pipeline
            dA = dA2; sA = sA2; rA = rA2;
            gg = gg2; act = act2;
        }
    }

    // global tail (n_edges % 4): last block, per-edge cursor atomics
    if (b == gridDim.x - 1) {
        for (int i = (n_grp << 2) + tid; i < n_edges; i += 1024) {
            const float d  = dist[i];
            const int   a  = s_zb[sender[i]];
            const u32   rv = (u32)recv[i];
            const int   bb = s_zb[rv];
            const float2 tu = s_tab[a];
            const float2 tv = s_tab[bb];
            const float rmax = tu.y + tv.y;
            if (d < rmax) {
                const float t   = __fdividef(d, rmax);
                const float roa = d * (tu.x + tv.x) * inv_pref;
                const float E0  = __expf(-e0 * roa);
                float phi;
                if (alleq) phi = csum * E0;
                else phi = c0 * E0 + c1 * __expf(-e1 * roa)
                         + c2 * __expf(-e2 * roa) + c3 * __expf(-e3 * roa);
                const float v   = 7.1998f * (float)(a * bb) * phi * __fdividef(1.0f, d);
                const float t2  = t * t;
                const float t6  = t2 * t2 * t2;
                const float o   = v * (1.0f - t6 * (28.0f - 48.0f * t + 21.0f * t2));
                const u32 rg    = rv / (u32)RS2;
                const u32 pos   = atomicAdd(&lcur[rg], 1u);
                if (pos < (u32)CAP)
                    seg[((size_t)b * Rr + rg) * CAP + pos] =
                        ((rv - rg * (u32)RS2) << 16) | bf16_rtn(o);
                else
                    unsafeAtomicAdd(&out[rv], o);
            }
        }
    }

    __syncthreads();
    if (tid < Rr)
        counts[b * Rr + tid] = min(lcur[tid], (u32)CAP);
}

// ---------- B: read each compacted range stream once, LDS accumulate --------
__global__ __launch_bounds__(1024, 2) void k_gather_accum(
    const u32* __restrict__ seg,
    const u32* __restrict__ counts,
    u16*       __restrict__ copies,
    int C_acc, int Rr)
{
    __shared__ float acc[RS2];
    const int c = blockIdx.x % C_acc;
    const int r = blockIdx.x / C_acc;
    const int tid = threadIdx.x;

    // prefetch first segment count while zeroing LDS
    u32 cnt = (c < EBLK) ? counts[c * Rr + r] : 0u;

    for (int i = tid; i < RS2; i += 1024) acc[i] = 0.0f;
    __syncthreads();

    for (int b = c; b < EBLK; b += C_acc) {
        const int bn = b + C_acc;
        const u32 cnt_next = (bn < EBLK) ? counts[bn * Rr + r] : 0u;
        const u32* __restrict__ p = seg + ((size_t)b * Rr + r) * CAP;
        for (u32 i = tid; i < cnt; i += 1024) {
            const u32 w = p[i];
            atomicAdd(&acc[w >> 16], __uint_as_float((w & 0xFFFFu) << 16));
        }
        cnt = cnt_next;
    }
    __syncthreads();

    // flush acc -> bf16 copies (RS2 multiple of 8)
    u16* __restrict__ dst = copies + ((size_t)c * Rr + r) * RS2;
    for (int i = tid * 8; i + 8 <= RS2; i += 8192) {
        const f32x4 a = *(const f32x4*)(acc + i);
        const f32x4 b = *(const f32x4*)(acc + i + 4);
        u32x4 o;
        o.x = bf16_rtn(a.x) | (bf16_rtn(a.y) << 16);
        o.y = bf16_rtn(a.z) | (bf16_rtn(a.w) << 16);
        o.z = bf16_rtn(b.x) | (bf16_rtn(b.y) << 16);
        o.w = bf16_rtn(b.z) | (bf16_rtn(b.w) << 16);
        *(u32x4*)(dst + i) = o;
    }
}

// ---------- C: out += sum of bf16 copies (out holds overflow atomics) -------
__global__ __launch_bounds__(256) void k_final5(
    const u32* __restrict__ copies32, float* __restrict__ out,
    int n_nodes, int C, int RRS32)
{
    const int p = blockIdx.x * 256 + threadIdx.x;    // pair index
    const int n = p << 1;
    if (n < n_nodes) {
        float s0 = 0.0f, s1 = 0.0f;
        #pragma unroll 4
        for (int c = 0; c < C; ++c) {
            const u32 w = copies32[(size_t)c * RRS32 + p];
            s0 += __uint_as_float(w << 16);
            s1 += __uint_as_float(w & 0xFFFF0000u);
        }
        if (n + 1 < n_nodes) {
            const float2 prev = *(const float2*)(out + n);
            *(float2*)(out + n) = make_float2(prev.x + s0, prev.y + s1);
        } else {
            out[n] += s0;
        }
    }
}

// ---------- fallback: LDS z-table + direct atomics ----------
__global__ __launch_bounds__(1024) void zbl_edge_lds(
    const int* __restrict__ z, const float* __restrict__ dist,
    const int* __restrict__ sender, const int* __restrict__ recv,
    const float* __restrict__ a_factor_p, const float* __restrict__ z_power_p,
    const float* __restrict__ coefs, const float* __restrict__ exps,
    const float* __restrict__ cradii, float* __restrict__ out,
    int n_edges, int n_words, int n_nodes)
{
    __shared__ u32    s_zw[ZW_WORDS];
    __shared__ float2 s_tab[N_ELEM];
    __shared__ float  s_coef[4], s_exp[4], s_inv;
    const int tid = threadIdx.x;
    build_ztab(s_zw, z, n_words, n_nodes, tid, 1024);
    if (tid < N_ELEM) {
        float zp = z_power_p[0];
        s_tab[tid] = make_float2(__powf((float)tid, zp), cradii[tid]);
    }
    if (tid < 4) { s_coef[tid] = coefs[tid]; s_exp[tid] = exps[tid]; }
    if (tid == 0) s_inv = 1.0f / (a_factor_p[0] * 0.529f);
    __syncthreads();
    const unsigned char* s_zb = (const unsigned char*)s_zw;
    const float inv_pref = s_inv;
    const int gstride = gridDim.x * 1024;
    for (int i = blockIdx.x * 1024 + tid; i < n_edges; i += gstride) {
        const float d  = dist[i];
        const int   a  = s_zb[sender[i]];
        const int   rv = recv[i];
        const int   b  = s_zb[rv];
        const float2 tu = s_tab[a];
        const float2 tv = s_tab[b];
        const float rmax = tu.y + tv.y;
        if (d < rmax) {
            const float t   = __fdividef(d, rmax);
            const float roa = d * (tu.x + tv.x) * inv_pref;
            const float phi = s_coef[0] * __expf(-s_exp[0] * roa)
                            + s_coef[1] * __expf(-s_exp[1] * roa)
                            + s_coef[2] * __expf(-s_exp[2] * roa)
                            + s_coef[3] * __expf(-s_exp[3] * roa);
            const float v   = 7.1998f * (float)(a * b) * phi * __fdividef(1.0f, d);
            const float t2  = t * t;
            const float t6  = t2 * t2 * t2;
            const float env = 1.0f - t6 * (28.0f - 48.0f * t + 21.0f * t2);
            unsafeAtomicAdd(&out[rv], v * env);
        }
    }
}

static inline size_t align16(size_t x) { return (x + 15) & ~(size_t)15; }

extern "C" void kernel_launch(void* const* d_in, const int* in_sizes, int n_in,
                              void* d_out, int out_size, void* d_ws, size_t ws_size,
                              hipStream_t stream) {
    const int*   z        = (const int*)d_in[0];
    const float* dist     = (const float*)d_in[1];
    const int*   eidx     = (const int*)d_in[2];
    const float* a_factor = (const float*)d_in[3];
    const float* z_power  = (const float*)d_in[4];
    const float* coefs    = (const float*)d_in[5];
    const float* exps     = (const float*)d_in[6];
    const float* cradii   = (const float*)d_in[7];
    float* out = (float*)d_out;

    const int n_edges = in_sizes[1];
    const int n_nodes = out_size;
    const int* sender = eidx;
    const int* recv   = eidx + n_edges;

    const int n_words = (n_nodes + 3) >> 2;
    const int R = (n_nodes + RS2 - 1) / RS2;

    // ws layout: [seg][counts][copies]
    const size_t seg_bytes = (size_t)EBLK * R * CAP * sizeof(u32);
    const size_t off_cnt   = align16(seg_bytes);
    const size_t off_cop   = align16(off_cnt + (size_t)EBLK * R * sizeof(u32));

    int C_acc = 0;
    if (R >= 1 && R <= MAX_R2 && n_nodes <= MAX_NODES) {
        const int opts[4] = {100, 50, 32, 16};
        for (int i = 0; i < 4; ++i) {
            size_t need = off_cop + (size_t)opts[i] * R * RS2 * sizeof(u16);
            if (ws_size >= need) { C_acc = opts[i]; break; }
        }
    }

    hipMemsetAsync(out, 0, (size_t)n_nodes * sizeof(float), stream);

    if (C_acc > 0) {
        char* ws = (char*)d_ws;
        u32* seg    = (u32*)ws;
        u32* counts = (u32*)(ws + off_cnt);
        u16* copies = (u16*)(ws + off_cop);

        const int n_grp = n_edges >> 2;                // 4-edge groups
        const int W = (n_grp + EBLK - 1) / EBLK;

        k_edge_split<<<EBLK, 1024, 0, stream>>>(
            z, dist, sender, recv, a_factor, z_power, coefs, exps, cradii,
            seg, counts, out, n_edges, n_words, n_nodes, W, R);
        k_gather_accum<<<C_acc * R, 1024, 0, stream>>>(seg, counts, copies, C_acc, R);
        k_final5<<<((n_nodes + 1) / 2 + 255) / 256, 256, 0, stream>>>(
            (const u32*)copies, out, n_nodes, C_acc, (R * RS2) >> 1);
    } else if (n_nodes <= MAX_NODES) {
        zbl_edge_lds<<<256, 1024, 0, stream>>>(
            z, dist, sender, recv, a_factor, z_power, coefs, exps, cradii,
            out, n_edges, n_words, n_nodes);
    }
}

// Round 20
// 73.267 us; speedup vs baseline: 1.0835x; 1.0835x over previous
//
#include <hip/hip_runtime.h>

#define N_ELEM 95
#define MAX_NODES 100096           // LDS z byte-table capacity
#define ZW_WORDS (MAX_NODES / 4)   // 25024 u32 words = 100096 B
#define RS2 20480                  // nodes per range (80 KB f32 acc in accum)
#define MAX_R2 5
#define EBLK 256                   // edge kernel blocks (1/CU, 100KB LDS)
#define CAP 4096                   // seg capacity per (block,range)

typedef float f32x4 __attribute__((ext_vector_type(4)));
typedef int   i32x4 __attribute__((ext_vector_type(4)));
typedef unsigned int u32;
typedef u32 u32x4 __attribute__((ext_vector_type(4)));
typedef unsigned long long u64;
typedef unsigned short u16;

__device__ __forceinline__ u32 bf16_rtn(float f) {           // f32 -> bf16 bits
    u32 u = __float_as_uint(f);
    return (u + 0x7FFFu + ((u >> 16) & 1u)) >> 16;
}

// build packed z byte-table in LDS directly from global z
__device__ __forceinline__ void build_ztab(
    u32* s_zw, const int* __restrict__ z, int n_words, int n_nodes, int tid, int nthr)
{
    for (int w = tid; w < n_words; w += nthr) {
        const int i = w << 2;
        u32 v;
        if (i + 4 <= n_nodes) {
            const i32x4 zz = ((const i32x4*)z)[w];
            v = ((u32)zz.x & 0xffu) | (((u32)zz.y & 0xffu) << 8)
              | (((u32)zz.z & 0xffu) << 16) | (((u32)zz.w & 0xffu) << 24);
        } else {
            v = 0u;
            for (int k = 0; k < 4 && i + k < n_nodes; ++k)
                v |= ((u32)z[i + k] & 0xffu) << (8 * k);
        }
        s_zw[w] = v;
    }
}

// ---------- A: compute values, emit surviving edges to per-range streams ----
// Full z byte-table in LDS (1 block/CU); rolling 2-stage load pipeline.
// Fast path: all screen_exps equal (wave-uniform) -> 1 expf/edge instead of 4.
__global__ __launch_bounds__(1024) void k_edge_split(
    const int*   __restrict__ z,
    const float* __restrict__ dist,
    const int*   __restrict__ sender,
    const int*   __restrict__ recv,
    const float* __restrict__ a_factor_p,
    const float* __restrict__ z_power_p,
    const float* __restrict__ coefs,
    const float* __restrict__ exps,
    const float* __restrict__ cradii,
    u32*         __restrict__ seg,      // [EBLK][Rr][CAP]
    u32*         __restrict__ counts,   // [EBLK][Rr]
    float*       __restrict__ out,      // pre-zeroed; receives overflow atomics
    int n_edges, int n_words, int n_nodes, int W, int Rr)
{
    __shared__ u32    s_zw[ZW_WORDS];
    __shared__ float2 s_tab[N_ELEM];    // {Z^Z_power, covalent_radius}
    __shared__ float  s_coef[4], s_exp[4], s_inv;
    __shared__ int    s_alleq;
    __shared__ u32    lcur[MAX_R2];         // block cursors per range
    __shared__ u32    s_base[16][MAX_R2];   // per-wave reserved bases

    const int tid  = threadIdx.x;
    const int lane = tid & 63;
    const int wid  = tid >> 6;

    build_ztab(s_zw, z, n_words, n_nodes, tid, 1024);
    if (tid < N_ELEM) {
        float zp = z_power_p[0];
        s_tab[tid] = make_float2(__powf((float)tid, zp), cradii[tid]);
    }
    if (tid < 4) { s_coef[tid] = coefs[tid]; s_exp[tid] = exps[tid]; }
    if (tid < MAX_R2) lcur[tid] = 0u;
    if (tid == 0) {
        s_inv = 1.0f / (a_factor_p[0] * 0.529f);
        s_alleq = (exps[0] == exps[1] && exps[1] == exps[2] && exps[2] == exps[3]);
    }
    __syncthreads();

    const unsigned char* s_zb = (const unsigned char*)s_zw;
    const float inv_pref = s_inv;
    const float c0 = s_coef[0], c1 = s_coef[1], c2 = s_coef[2], c3 = s_coef[3];
    const float e0 = s_exp[0],  e1 = s_exp[1],  e2 = s_exp[2],  e3 = s_exp[3];
    const float csum  = c0 + c1 + c2 + c3;
    const bool  alleq = (s_alleq != 0);

    const int n_grp = n_edges >> 3;     // groups of 8 edges
    const int b     = blockIdx.x;
    const int g0    = b * W;
    const int g1    = min(n_grp, g0 + W);

    if (g0 < g1) {
        const int n_iter = (g1 - g0 + 1023) >> 10;

        // stage 0: load iteration 0 (addresses clamped -> unconditional)
        int  gg  = g0 + tid;
        bool act = (gg < g1);
        int  g   = act ? gg : (g1 - 1);
        f32x4 dA = ((const f32x4*)dist)[2 * g];
        f32x4 dB = ((const f32x4*)dist)[2 * g + 1];
        i32x4 sA = ((const i32x4*)sender)[2 * g];
        i32x4 sB = ((const i32x4*)sender)[2 * g + 1];
        i32x4 rA = ((const i32x4*)recv)[2 * g];
        i32x4 rB = ((const i32x4*)recv)[2 * g + 1];

        for (int it = 0; it < n_iter; ++it) {
            // prefetch next iteration's 6 vector loads
            const int  gg2  = gg + 1024;
            const bool act2 = (gg2 < g1);
            const int  g2   = act2 ? gg2 : (g1 - 1);
            const f32x4 dA2 = ((const f32x4*)dist)[2 * g2];
            const f32x4 dB2 = ((const f32x4*)dist)[2 * g2 + 1];
            const i32x4 sA2 = ((const i32x4*)sender)[2 * g2];
            const i32x4 sB2 = ((const i32x4*)sender)[2 * g2 + 1];
            const i32x4 rA2 = ((const i32x4*)recv)[2 * g2];
            const i32x4 rB2 = ((const i32x4*)recv)[2 * g2 + 1];

            float dd[8] = {dA.x, dA.y, dA.z, dA.w, dB.x, dB.y, dB.z, dB.w};
            int   ss[8] = {sA.x, sA.y, sA.z, sA.w, sB.x, sB.y, sB.z, sB.w};
            int   rr[8] = {rA.x, rA.y, rA.z, rA.w, rB.x, rB.y, rB.z, rB.w};

            int zu[8], zv[8];
            #pragma unroll
            for (int k = 0; k < 8; ++k) zu[k] = s_zb[ss[k]];
            #pragma unroll
            for (int k = 0; k < 8; ++k) zv[k] = s_zb[rr[k]];

            bool  em[8];
            float val[8];
            u32   entry[8], rgk[8];
            u64   cnt_pk = 0ull;

            #pragma unroll
            for (int k = 0; k < 8; ++k) {
                const float d = dd[k];
                const float2 tu = s_tab[zu[k]];
                const float2 tv = s_tab[zv[k]];
                const float powsum = tu.x + tv.x;
                const float rmax   = tu.y + tv.y;
                em[k] = act && (d < rmax);
                float o = 0.0f;
                if (em[k]) {
                    const float t   = __fdividef(d, rmax);
                    const float roa = d * powsum * inv_pref;
                    const float E0  = __expf(-e0 * roa);
                    float phi;
                    if (alleq) {
                        phi = csum * E0;           // 1 expf (uniform fast path)
                    } else {
                        phi = c0 * E0
                            + c1 * __expf(-e1 * roa)
                            + c2 * __expf(-e2 * roa)
                            + c3 * __expf(-e3 * roa);
                    }
                    const float v   = 7.1998f * (float)(zu[k] * zv[k]) * phi
                                    * __fdividef(1.0f, d);
                    const float t2  = t * t;
                    const float t6  = t2 * t2 * t2;
                    // p=6: 1 - 28 t^6 + 48 t^7 - 21 t^8
                    o = v * (1.0f - t6 * (28.0f - 48.0f * t + 21.0f * t2));
                }
                val[k] = o;
                const u32 rv  = (u32)rr[k];
                const u32 rg  = rv / (u32)RS2;
                rgk[k] = rg;
                entry[k] = ((rv - rg * (u32)RS2) << 16) | bf16_rtn(o);
                if (em[k]) cnt_pk += 1ull << (12 * rg);
            }

            // wave-wide inclusive scan of packed per-range counts (12-bit)
            u64 v = cnt_pk;
            #pragma unroll
            for (int d = 1; d < 64; d <<= 1) {
                u64 t = __shfl_up(v, (unsigned)d, 64);
                if (lane >= d) v += t;
            }
            const u64 excl = v - cnt_pk;

            // lane 63 holds wave totals: reserve block-level bases per range
            if (lane == 63) {
                for (int r = 0; r < Rr; ++r) {
                    const u32 tot = (u32)(v >> (12 * r)) & 0xFFFu;
                    s_base[wid][r] = tot ? atomicAdd(&lcur[r], tot) : lcur[r];
                }
            }

            // emit
            u64 run_pk = 0ull;
            #pragma unroll
            for (int k = 0; k < 8; ++k) {
                if (em[k]) {
                    const u32 rg  = rgk[k];
                    const u32 off = ((u32)(excl >> (12 * rg)) & 0xFFFu)
                                  + ((u32)(run_pk >> (12 * rg)) & 0xFFFu);
                    run_pk += 1ull << (12 * rg);
                    const u32 pos = s_base[wid][rg] + off;
                    if (pos < (u32)CAP)
                        seg[((size_t)b * Rr + rg) * CAP + pos] = entry[k];
                    else
                        unsafeAtomicAdd(&out[rr[k]], val[k]);
                }
            }

            // rotate pipeline
            dA = dA2; dB = dB2; sA = sA2; sB = sB2; rA = rA2; rB = rB2;
            gg = gg2; act = act2;
        }
    }

    // global tail (n_edges % 8): last block, per-edge cursor atomics
    if (b == gridDim.x - 1) {
        for (int i = (n_grp << 3) + tid; i < n_edges; i += 1024) {
            const float d  = dist[i];
            const int   a  = s_zb[sender[i]];
            const u32   rv = (u32)recv[i];
            const int   bb = s_zb[rv];
            const float2 tu = s_tab[a];
            const float2 tv = s_tab[bb];
            const float rmax = tu.y + tv.y;
            if (d < rmax) {
                const float t   = __fdividef(d, rmax);
                const float roa = d * (tu.x + tv.x) * inv_pref;
                const float E0  = __expf(-e0 * roa);
                float phi;
                if (alleq) phi = csum * E0;
                else phi = c0 * E0 + c1 * __expf(-e1 * roa)
                         + c2 * __expf(-e2 * roa) + c3 * __expf(-e3 * roa);
                const float v   = 7.1998f * (float)(a * bb) * phi * __fdividef(1.0f, d);
                const float t2  = t * t;
                const float t6  = t2 * t2 * t2;
                const float o   = v * (1.0f - t6 * (28.0f - 48.0f * t + 21.0f * t2));
                const u32 rg    = rv / (u32)RS2;
                const u32 pos   = atomicAdd(&lcur[rg], 1u);
                if (pos < (u32)CAP)
                    seg[((size_t)b * Rr + rg) * CAP + pos] =
                        ((rv - rg * (u32)RS2) << 16) | bf16_rtn(o);
                else
                    unsafeAtomicAdd(&out[rv], o);
            }
        }
    }

    __syncthreads();
    if (tid < Rr)
        counts[b * Rr + tid] = min(lcur[tid], (u32)CAP);
}

// ---------- B: read each compacted range stream once, LDS accumulate --------
__global__ __launch_bounds__(1024, 2) void k_gather_accum(
    const u32* __restrict__ seg,
    const u32* __restrict__ counts,
    u16*       __restrict__ copies,
    int C_acc, int Rr)
{
    __shared__ float acc[RS2];
    const int c = blockIdx.x % C_acc;
    const int r = blockIdx.x / C_acc;
    const int tid = threadIdx.x;

    // prefetch first segment count while zeroing LDS
    u32 cnt = (c < EBLK) ? counts[c * Rr + r] : 0u;

    for (int i = tid; i < RS2; i += 1024) acc[i] = 0.0f;
    __syncthreads();

    for (int b = c; b < EBLK; b += C_acc) {
        const int bn = b + C_acc;
        const u32 cnt_next = (bn < EBLK) ? counts[bn * Rr + r] : 0u;
        const u32* __restrict__ p = seg + ((size_t)b * Rr + r) * CAP;
        for (u32 i = tid; i < cnt; i += 1024) {
            const u32 w = p[i];
            atomicAdd(&acc[w >> 16], __uint_as_float((w & 0xFFFFu) << 16));
        }
        cnt = cnt_next;
    }
    __syncthreads();

    // flush acc -> bf16 copies (RS2 multiple of 8)
    u16* __restrict__ dst = copies + ((size_t)c * Rr + r) * RS2;
    for (int i = tid * 8; i + 8 <= RS2; i += 8192) {
        const f32x4 a = *(const f32x4*)(acc + i);
        const f32x4 b = *(const f32x4*)(acc + i + 4);
        u32x4 o;
        o.x = bf16_rtn(a.x) | (bf16_rtn(a.y) << 16);
        o.y = bf16_rtn(a.z) | (bf16_rtn(a.w) << 16);
        o.z = bf16_rtn(b.x) | (bf16_rtn(b.y) << 16);
        o.w = bf16_rtn(b.z) | (bf16_rtn(b.w) << 16);
        *(u32x4*)(dst + i) = o;
    }
}

// ---------- C: out += sum of bf16 copies (out holds overflow atomics) -------
__global__ __launch_bounds__(256) void k_final5(
    const u32* __restrict__ copies32, float* __restrict__ out,
    int n_nodes, int C, int RRS32)
{
    const int p = blockIdx.x * 256 + threadIdx.x;    // pair index
    const int n = p << 1;
    if (n < n_nodes) {
        float s0 = 0.0f, s1 = 0.0f;
        #pragma unroll 8
        for (int c = 0; c < C; ++c) {
            const u32 w = copies32[(size_t)c * RRS32 + p];
            s0 += __uint_as_float(w << 16);
            s1 += __uint_as_float(w & 0xFFFF0000u);
        }
        if (n + 1 < n_nodes) {
            const float2 prev = *(const float2*)(out + n);
            *(float2*)(out + n) = make_float2(prev.x + s0, prev.y + s1);
        } else {
            out[n] += s0;
        }
    }
}

// ---------- fallback: LDS z-table + direct atomics ----------
__global__ __launch_bounds__(1024) void zbl_edge_lds(
    const int* __restrict__ z, const float* __restrict__ dist,
    const int* __restrict__ sender, const int* __restrict__ recv,
    const float* __restrict__ a_factor_p, const float* __restrict__ z_power_p,
    const float* __restrict__ coefs, const float* __restrict__ exps,
    const float* __restrict__ cradii, float* __restrict__ out,
    int n_edges, int n_words, int n_nodes)
{
    __shared__ u32    s_zw[ZW_WORDS];
    __shared__ float2 s_tab[N_ELEM];
    __shared__ float  s_coef[4], s_exp[4], s_inv;
    const int tid = threadIdx.x;
    build_ztab(s_zw, z, n_words, n_nodes, tid, 1024);
    if (tid < N_ELEM) {
        float zp = z_power_p[0];
        s_tab[tid] = make_float2(__powf((float)tid, zp), cradii[tid]);
    }
    if (tid < 4) { s_coef[tid] = coefs[tid]; s_exp[tid] = exps[tid]; }
    if (tid == 0) s_inv = 1.0f / (a_factor_p[0] * 0.529f);
    __syncthreads();
    const unsigned char* s_zb = (const unsigned char*)s_zw;
    const float inv_pref = s_inv;
    const int gstride = gridDim.x * 1024;
    for (int i = blockIdx.x * 1024 + tid; i < n_edges; i += gstride) {
        const float d  = dist[i];
        const int   a  = s_zb[sender[i]];
        const int   rv = recv[i];
        const int   b  = s_zb[rv];
        const float2 tu = s_tab[a];
        const float2 tv = s_tab[b];
        const float rmax = tu.y + tv.y;
        if (d < rmax) {
            const float t   = __fdividef(d, rmax);
            const float roa = d * (tu.x + tv.x) * inv_pref;
            const float phi = s_coef[0] * __expf(-s_exp[0] * roa)
                            + s_coef[1] * __expf(-s_exp[1] * roa)
                            + s_coef[2] * __expf(-s_exp[2] * roa)
                            + s_coef[3] * __expf(-s_exp[3] * roa);
            const float v   = 7.1998f * (float)(a * b) * phi * __fdividef(1.0f, d);
            const float t2  = t * t;
            const float t6  = t2 * t2 * t2;
            const float env = 1.0f - t6 * (28.0f - 48.0f * t + 21.0f * t2);
            unsafeAtomicAdd(&out[rv], v * env);
        }
    }
}

static inline size_t align16(size_t x) { return (x + 15) & ~(size_t)15; }

extern "C" void kernel_launch(void* const* d_in, const int* in_sizes, int n_in,
                              void* d_out, int out_size, void* d_ws, size_t ws_size,
                              hipStream_t stream) {
    const int*   z        = (const int*)d_in[0];
    const float* dist     = (const float*)d_in[1];
    const int*   eidx     = (const int*)d_in[2];
    const float* a_factor = (const float*)d_in[3];
    const float* z_power  = (const float*)d_in[4];
    const float* coefs    = (const float*)d_in[5];
    const float* exps     = (const float*)d_in[6];
    const float* cradii   = (const float*)d_in[7];
    float* out = (float*)d_out;

    const int n_edges = in_sizes[1];
    const int n_nodes = out_size;
    const int* sender = eidx;
    const int* recv   = eidx + n_edges;

    const int n_words = (n_nodes + 3) >> 2;
    const int R = (n_nodes + RS2 - 1) / RS2;

    // ws layout: [seg][counts][copies]
    const size_t seg_bytes = (size_t)EBLK * R * CAP * sizeof(u32);
    const size_t off_cnt   = align16(seg_bytes);
    const size_t off_cop   = align16(off_cnt + (size_t)EBLK * R * sizeof(u32));

    int C_acc = 0;
    if (R >= 1 && R <= MAX_R2 && n_nodes <= MAX_NODES) {
        const int opts[3] = {50, 32, 16};
        for (int i = 0; i < 3; ++i) {
            size_t need = off_cop + (size_t)opts[i] * R * RS2 * sizeof(u16);
            if (ws_size >= need) { C_acc = opts[i]; break; }
        }
    }

    hipMemsetAsync(out, 0, (size_t)n_nodes * sizeof(float), stream);

    if (C_acc > 0) {
        char* ws = (char*)d_ws;
        u32* seg    = (u32*)ws;
        u32* counts = (u32*)(ws + off_cnt);
        u16* copies = (u16*)(ws + off_cop);

        const int n_grp = n_edges >> 3;
        const int W = (n_grp + EBLK - 1) / EBLK;

        k_edge_split<<<EBLK, 1024, 0, stream>>>(
            z, dist, sender, recv, a_factor, z_power, coefs, exps, cradii,
            seg, counts, out, n_edges, n_words, n_nodes, W, R);
        k_gather_accum<<<C_acc * R, 1024, 0, stream>>>(seg, counts, copies, C_acc, R);
        k_final5<<<((n_nodes + 1) / 2 + 255) / 256, 256, 0, stream>>>(
            (const u32*)copies, out, n_nodes, C_acc, (R * RS2) >> 1);
    } else if (n_nodes <= MAX_NODES) {
        zbl_edge_lds<<<256, 1024, 0, stream>>>(
            z, dist, sender, recv, a_factor, z_power, coefs, exps, cradii,
            out, n_edges, n_words, n_nodes);
    }
}